// Round 3
// baseline (145.422 us; speedup 1.0000x reference)
//
#include <hip/hip_runtime.h>
#include <hip/hip_bf16.h>

// B=8, H=W=32 (seq=1024), C=512, heads=8, head_dim=64, groups=32
#define SEQ   1024
#define CH    512
#define NHEAD 8
#define HDIM  64
#define BATCH 8

using short8  = __attribute__((ext_vector_type(8))) short;
using short4v = __attribute__((ext_vector_type(4))) short;
using floatx4 = __attribute__((ext_vector_type(4))) float;
using uint4v  = __attribute__((ext_vector_type(4))) unsigned int;

#if __has_builtin(__builtin_amdgcn_exp2f)
#define EXP2F __builtin_amdgcn_exp2f
#else
#define EXP2F exp2f
#endif

__device__ inline unsigned short f2bf(float f) {
  __hip_bfloat16 h = __float2bfloat16(f);
  return __builtin_bit_cast(unsigned short, h);
}

// packed f32x2 -> bf16x2 (RNE), single VALU inst
__device__ inline unsigned int cvt_pk_bf16(float lo, float hi) {
  unsigned int r;
  asm("v_cvt_pk_bf16_f32 %0, %1, %2" : "=v"(r) : "v"(lo), "v"(hi));
  return r;
}

// async 16B global->LDS DMA (lane-linear LDS dest required)
__device__ inline void load_lds16(const void* g, void* l) {
  __builtin_amdgcn_global_load_lds(
      (const __attribute__((address_space(1))) unsigned int*)g,
      (__attribute__((address_space(3))) unsigned int*)l, 16, 0, 0);
}

// ---------------------------------------------------------------------------
// K1 (fused): blocks 0..255 = GroupNorm for one (b,g): the whole 1024x16
// slice (64 KB) is staged in LDS, stats computed in one pass, normalized
// bf16 written back -- x is read ONCE.
// Blocks 256..447: wqkv transpose (64x64 tiles); 448..511: wout transpose.
// ---------------------------------------------------------------------------
__global__ __launch_bounds__(1024) void prep_kernel(
    const float* __restrict__ wqkv, const float* __restrict__ wout,
    const float* __restrict__ x, const float* __restrict__ gsc,
    const float* __restrict__ gbs,
    unsigned short* __restrict__ wqkvt, unsigned short* __restrict__ woutt,
    unsigned short* __restrict__ xn) {
  __shared__ float SH[16416];   // 64 KB tile + 32 floats reduce scratch
  const int blk = blockIdx.x, tid = threadIdx.x;

  if (blk >= 256) {
    // ---- weight transpose, 64x64 tile, bf16 out ----
    const float* src; unsigned short* dst; int C, bx, by;
    if (blk < 448) { int t = blk - 256; src = wqkv; dst = wqkvt; C = 1536; bx = t % 24; by = t / 24; }
    else           { int t = blk - 448; src = wout; dst = woutt; C = 512;  bx = t & 7;  by = t >> 3; }
    float (*T)[65] = (float(*)[65])SH;
    int tx = tid & 63, ty = tid >> 6;            // ty 0..15
    for (int j = 0; j < 4; ++j)
      T[ty + j * 16][tx] = src[(size_t)(by * 64 + ty + j * 16) * C + bx * 64 + tx];
    __syncthreads();
    for (int j = 0; j < 4; ++j)
      dst[(size_t)(bx * 64 + ty + j * 16) * 512 + by * 64 + tx] = f2bf(T[tx][ty + j * 16]);
    return;
  }

  // ---- GroupNorm, one (b,g) per block ----
  const int b = blk >> 5, g = blk & 31;
  const size_t base = (size_t)b * SEQ * CH + g * 16;

  float s = 0.f, sq = 0.f;
  for (int i = 0; i < 4; ++i) {
    int c = (i << 10) + tid;                     // 4096 float4 chunks
    int r = c >> 2, c4 = (c & 3) << 2;
    float4 v = *(const float4*)(x + base + (size_t)r * CH + c4);
    *(float4*)&SH[c << 2] = v;
    s  += v.x + v.y + v.z + v.w;
    sq += v.x * v.x + v.y * v.y + v.z * v.z + v.w * v.w;
  }
  for (int off = 1; off < 64; off <<= 1) {
    s  += __shfl_xor(s, off);
    sq += __shfl_xor(sq, off);
  }
  const int wid = tid >> 6, lane = tid & 63;
  if (lane == 0) { SH[16384 + wid] = s; SH[16400 + wid] = sq; }
  __syncthreads();
  float ts = 0.f, tq = 0.f;
  for (int i = 0; i < 16; ++i) { ts += SH[16384 + i]; tq += SH[16400 + i]; }
  const float inv_n = 1.0f / 16384.0f;
  float mean = ts * inv_n;
  float var  = tq * inv_n - mean * mean;
  float rstd = rsqrtf(var + 1e-6f);

  int c4 = (tid & 3) << 2;
  float4 sc = *(const float4*)(gsc + g * 16 + c4);
  float4 bs = *(const float4*)(gbs + g * 16 + c4);
  for (int i = 0; i < 4; ++i) {
    int c = (i << 10) + tid;
    int r = c >> 2;
    float4 v = *(const float4*)&SH[c << 2];
    ushort4 o;
    o.x = f2bf((v.x - mean) * rstd * sc.x + bs.x);
    o.y = f2bf((v.y - mean) * rstd * sc.y + bs.y);
    o.z = f2bf((v.z - mean) * rstd * sc.z + bs.z);
    o.w = f2bf((v.w - mean) * rstd * sc.w + bs.w);
    *(ushort4*)(xn + base + (size_t)r * CH + c4) = o;
  }
}

// ---------------------------------------------------------------------------
// K2/K4: GEMM C = A(MxK) * Bt(NxK)^T, bf16 in, fp32 acc, MTILE x 128 tile.
// Grid is (m-tile, n-tile) so blocks sharing an A-tile get the same
// linear%8 -> same XCD (L2 locality).  BK=64, global_load_lds staging,
// XOR-swizzled LDS.  Epilogues via LDS -> 16B global stores.
// EPI 0 (MTILE=128, QKV): +bias; q scaled (1/64)*log2e; q/k -> (h,s,d);
//     v -> transposed vt (h,d,s) with s permuted within 32-blocks so attn
//     PV P-frags form 16x16x32 A-operands with zero cross-lane ops.
// EPI 1 (MTILE=64, out):  +bias +residual, fp32 out.
// ---------------------------------------------------------------------------
template <int EPI, int MTILE>
__global__ __launch_bounds__(256) void gemm_bt_kernel(
    const unsigned short* __restrict__ A, const unsigned short* __restrict__ Bt,
    int K, int N,
    const float* __restrict__ bias, const float* __restrict__ resid,
    float* __restrict__ outf,
    unsigned short* __restrict__ qb, unsigned short* __restrict__ kb,
    unsigned short* __restrict__ vtb) {
  constexpr int SMSZ = (MTILE == 128) ? 17408 : 16896;
  constexpr int NI   = (MTILE == 128) ? 4 : 2;
  __shared__ alignas(16) unsigned short SM[SMSZ];
  unsigned short* LA = SM;                 // MTILE x 64, swizzled
  unsigned short* LB = SM + MTILE * 64;    // 128 x 64, swizzled

  const int tid = threadIdx.x;
  const int wid = tid >> 6, lane = tid & 63;
  const int quad = lane >> 4, m16 = lane & 15;
  const int sw = m16 & 7;
  const int wm = (MTILE == 128) ? (wid & 1) * 64 : 0;
  const int wn = (MTILE == 128) ? (wid >> 1) * 64 : wid * 32;
  const int m0 = blockIdx.x * MTILE, n0 = blockIdx.y * 128;

  floatx4 acc[4][NI];
  for (int i = 0; i < 4; ++i)
    for (int j = 0; j < NI; ++j) acc[i][j] = 0.f;

  for (int k0 = 0; k0 < K; k0 += 64) {
    for (int i = 0; i < MTILE / 32; ++i) {
      int c = i * 256 + tid;
      int r = c >> 3, kc = c & 7;
      load_lds16(A + (size_t)(m0 + r) * K + k0 + ((kc ^ (r & 7)) << 3), &LA[c << 3]);
    }
    for (int i = 0; i < 4; ++i) {
      int c = i * 256 + tid;
      int r = c >> 3, kc = c & 7;
      load_lds16(Bt + (size_t)(n0 + r) * K + k0 + ((kc ^ (r & 7)) << 3), &LB[c << 3]);
    }
    __syncthreads();
    for (int kq = 0; kq < 2; ++kq) {
      int csw = (((kq << 2) + quad) ^ sw) << 3;
      short8 af[4], bf[NI];
      for (int mi = 0; mi < 4; ++mi)
        af[mi] = *(const short8*)&LA[(wm + mi * 16 + m16) * 64 + csw];
      for (int ni = 0; ni < NI; ++ni)
        bf[ni] = *(const short8*)&LB[(wn + ni * 16 + m16) * 64 + csw];
      for (int mi = 0; mi < 4; ++mi)
        for (int ni = 0; ni < NI; ++ni)
          acc[mi][ni] = __builtin_amdgcn_mfma_f32_16x16x32_bf16(af[mi], bf[ni], acc[mi][ni], 0, 0, 0);
    }
    __syncthreads();
  }

  // C/D layout: row = quad*4+reg, col = lane&15
  const int b = m0 >> 10;
  if (EPI == 0) {
    const int part = n0 >> 9;                // 0=q 1=k 2=v (block-uniform)
    if (part < 2) {
      const float qscale = (part == 0) ? 0.0225421381f : 1.0f;  // (1/64)*log2e
      unsigned short* dst = (part == 0) ? qb : kb;
      for (int mi = 0; mi < 4; ++mi)
        for (int ni = 0; ni < 4; ++ni) {
          int ln = wn + ni * 16 + m16;
          float bb = bias[n0 + ln];
          for (int reg = 0; reg < 4; ++reg)
            SM[(wm + mi * 16 + quad * 4 + reg) * 136 + ln] =
                f2bf((acc[mi][ni][reg] + bb) * qscale);
        }
      __syncthreads();
      const int colb = n0 & 511;
      for (int j = 0; j < 8; ++j) {
        int c = j * 256 + tid;               // 2048 16B chunks
        int m = c >> 4, n8 = (c & 15) * 8;
        int h = (colb + n8) >> 6, d = n8 & 63;
        int sp = (m0 & 1023) + m;
        int4 v = *(const int4*)&SM[m * 136 + n8];
        *(int4*)(dst + (((size_t)(b * NHEAD + h)) * SEQ + sp) * HDIM + d) = v;
      }
    } else {
      // v: transpose [n][m], m permuted within 32-blocks (slot = 32*(mblk>>1)
      // + 8*quad + 4*(mblk&1) + reg) for attn's K=32 PV A-operands
      for (int mi = 0; mi < 4; ++mi)
        for (int ni = 0; ni < 4; ++ni) {
          int ln = wn + ni * 16 + m16;
          float bb = bias[n0 + ln];
          int mblk = (wm >> 4) + mi;
          int sbase = 32 * (mblk >> 1) + 8 * quad + 4 * (mblk & 1);
          for (int reg = 0; reg < 4; ++reg)
            SM[ln * 136 + sbase + reg] = f2bf(acc[mi][ni][reg] + bb);
        }
      __syncthreads();
      int hbase = (n0 - 1024) >> 6;
      for (int j = 0; j < 8; ++j) {
        int c = j * 256 + tid;
        int ld = c >> 4, sp8 = (c & 15) * 8;
        int h = hbase + (ld >> 6), d = ld & 63;
        int4 v = *(const int4*)&SM[ld * 136 + sp8];
        *(int4*)(vtb + ((size_t)(b * NHEAD + h) * HDIM + d) * SEQ + (m0 & 1023) + sp8) = v;
      }
    }
  } else {
    float* SMf = (float*)SM;                 // 64 x 132 fp32
    for (int mi = 0; mi < 4; ++mi)
      for (int ni = 0; ni < NI; ++ni) {
        int ln = wn + ni * 16 + m16;
        float bb = bias[n0 + ln];
        for (int reg = 0; reg < 4; ++reg)
          SMf[(mi * 16 + quad * 4 + reg) * 132 + ln] = acc[mi][ni][reg] + bb;
      }
    __syncthreads();
    for (int j = 0; j < 8; ++j) {
      int c = j * 256 + tid;                 // 2048 float4 chunks
      int m = c >> 5, n4 = (c & 31) * 4;
      size_t idx = (size_t)(m0 + m) * N + n0 + n4;
      float4 v = *(const float4*)&SMf[m * 132 + n4];
      float4 rr = *(const float4*)&resid[idx];
      v.x += rr.x; v.y += rr.y; v.z += rr.z; v.w += rr.w;
      *(float4*)&outf[idx] = v;
    }
  }
}

// ---------------------------------------------------------------------------
// K3: flash attention.  LDS-read-bound analysis (r2): each wave read the full
// K/V tile (32 KB) per kt as ds_read_b128 -- 16 waves/CU x 8 kt x 32 reads
// x ~12 cyc ~= 20 us/CU of pure LDS traffic vs ~2 us of MFMA.  Fix: 2x
// FLOP per LDS byte -- 4 waves x 32 q-rows each (two Q column-blocks in
// registers); every K-frag / V-frag read now feeds TWO MFMAs.  Grid and LDS
// unchanged (64KB, 2 blocks/CU); per-CU LDS reads halve.
// Keeps: 2-phase dbuf staging, setprio, raw v_exp_f32, packed cvt_pk_bf16,
// denominator via ones-column MFMA (D-layout matches o -- no shuffles).
// ---------------------------------------------------------------------------
__global__ __launch_bounds__(256) void attn_kernel(
    const unsigned short* __restrict__ qb, const unsigned short* __restrict__ kb,
    const unsigned short* __restrict__ vtb, unsigned short* __restrict__ ao) {
  const int head = blockIdx.x, qt = blockIdx.y;
  const int b = head >> 3, h = head & 7;
  const int tid = threadIdx.x;
  const int wid = tid >> 6, lane = tid & 63;
  const int quad = lane >> 4, m16 = lane & 15;
  const int sw = m16 & 7;

  __shared__ alignas(16) unsigned short sK[2][8192];   // 128x64, swizzled
  __shared__ alignas(16) unsigned short sV[2][8192];   // Vt 64x128 (s permuted), swizzled

  const unsigned short* kbase = kb  + (size_t)head * SEQ * HDIM;
  const unsigned short* vbase = vtb + (size_t)head * HDIM * SEQ;

  // Q fragments for two 16-row q-blocks (pre-scaled by (1/64)*log2e upstream)
  short8 aq[2][2];
  for (int qblk = 0; qblk < 2; ++qblk) {
    const size_t qrow = (size_t)head * SEQ + qt * 128 + wid * 32 + qblk * 16 + m16;
    aq[qblk][0] = *(const short8*)(qb + qrow * HDIM + quad * 8);
    aq[qblk][1] = *(const short8*)(qb + qrow * HDIM + 32 + quad * 8);
  }

  const unsigned int onep = 0x3F803F80u;               // bf16(1.0) x2
  const short8 vones = __builtin_bit_cast(short8, (uint4v){onep, onep, onep, onep});

  floatx4 la[2];                                       // denominators, D-layout
  floatx4 o[2][4];
  for (int qblk = 0; qblk < 2; ++qblk) {
    la[qblk] = 0.f;
    for (int df = 0; df < 4; ++df) o[qblk][df] = 0.f;
  }

  // prologue: stage tile 0 into buffer 0 (256 threads -> 4 chunks each)
  for (int i = 0; i < 4; ++i) {
    int c = i * 256 + tid;
    int r = c >> 3, kc = c & 7;
    load_lds16(kbase + r * HDIM + ((kc ^ (r & 7)) << 3), &sK[0][c << 3]);
  }
  for (int i = 0; i < 4; ++i) {
    int c = i * 256 + tid;
    int d = c >> 4, kc = c & 15;
    load_lds16(vbase + d * SEQ + ((kc ^ (d & 7)) << 3), &sV[0][c << 3]);
  }
  __syncthreads();

  int buf = 0;
  for (int kt = 0; kt < 8; ++kt) {
    // issue next tile's staging into the other buffer (overlaps compute;
    // drained by the vmcnt(0) inside the end-of-iteration __syncthreads)
    if (kt < 7) {
      const int nb = buf ^ 1, kn = kt + 1;
      for (int i = 0; i < 4; ++i) {
        int c = i * 256 + tid;
        int r = c >> 3, kc = c & 7;
        load_lds16(kbase + (kn * 128 + r) * HDIM + ((kc ^ (r & 7)) << 3), &sK[nb][c << 3]);
      }
      for (int i = 0; i < 4; ++i) {
        int c = i * 256 + tid;
        int d = c >> 4, kc = c & 15;
        load_lds16(vbase + d * SEQ + kn * 128 + ((kc ^ (d & 7)) << 3), &sV[nb][c << 3]);
      }
    }

    // St = K*Q^T; exp2 + packed bf16 cvt.  K-frags k0/k1 feed BOTH q-blocks.
    // sf=2u+t -> A-operand k=quad*8+4t+r
    unsigned int pw[2][4][4];
    for (int sf = 0; sf < 8; ++sf) {
      const int rb = (sf * 16 + m16) * 64;
      short8 k0 = *(const short8*)&sK[buf][rb + ((quad ^ sw) << 3)];
      short8 k1 = *(const short8*)&sK[buf][rb + (((4 + quad) ^ sw) << 3)];
      floatx4 s0 = 0.f, s1 = 0.f;
      __builtin_amdgcn_s_setprio(1);
      s0 = __builtin_amdgcn_mfma_f32_16x16x32_bf16(k0, aq[0][0], s0, 0, 0, 0);
      s0 = __builtin_amdgcn_mfma_f32_16x16x32_bf16(k1, aq[0][1], s0, 0, 0, 0);
      s1 = __builtin_amdgcn_mfma_f32_16x16x32_bf16(k0, aq[1][0], s1, 0, 0, 0);
      s1 = __builtin_amdgcn_mfma_f32_16x16x32_bf16(k1, aq[1][1], s1, 0, 0, 0);
      __builtin_amdgcn_s_setprio(0);
      const int u = sf >> 1, w2 = (sf & 1) * 2;
      {
        float p0 = EXP2F(s0[0]), p1 = EXP2F(s0[1]);
        float p2 = EXP2F(s0[2]), p3 = EXP2F(s0[3]);
        pw[0][u][w2 + 0] = cvt_pk_bf16(p0, p1);
        pw[0][u][w2 + 1] = cvt_pk_bf16(p2, p3);
      }
      {
        float p0 = EXP2F(s1[0]), p1 = EXP2F(s1[1]);
        float p2 = EXP2F(s1[2]), p3 = EXP2F(s1[3]);
        pw[1][u][w2 + 0] = cvt_pk_bf16(p0, p1);
        pw[1][u][w2 + 1] = cvt_pk_bf16(p2, p3);
      }
    }

    // O += P*V  (K=32: B-frag = 8 consecutive permuted slots, b128);
    // each V-frag bv feeds both q-blocks.  la += P*ones -> denominator.
    for (int u = 0; u < 4; ++u) {
      const short8 pf0 = __builtin_bit_cast(
          short8, (uint4v){pw[0][u][0], pw[0][u][1], pw[0][u][2], pw[0][u][3]});
      const short8 pf1 = __builtin_bit_cast(
          short8, (uint4v){pw[1][u][0], pw[1][u][1], pw[1][u][2], pw[1][u][3]});
      const int chunk = ((u * 4 + quad) ^ sw) << 3;
      __builtin_amdgcn_s_setprio(1);
      for (int df = 0; df < 4; ++df) {
        short8 bv = *(const short8*)&sV[buf][(df * 16 + m16) * 128 + chunk];
        o[0][df] = __builtin_amdgcn_mfma_f32_16x16x32_bf16(pf0, bv, o[0][df], 0, 0, 0);
        o[1][df] = __builtin_amdgcn_mfma_f32_16x16x32_bf16(pf1, bv, o[1][df], 0, 0, 0);
      }
      la[0] = __builtin_amdgcn_mfma_f32_16x16x32_bf16(pf0, vones, la[0], 0, 0, 0);
      la[1] = __builtin_amdgcn_mfma_f32_16x16x32_bf16(pf1, vones, la[1], 0, 0, 0);
      __builtin_amdgcn_s_setprio(0);
    }
    __syncthreads();
    buf ^= 1;
  }

  // normalize: la[qblk][r] is the denominator for its q-row (any column) --
  // identical layout to o, so no cross-lane reduction is needed.
  for (int qblk = 0; qblk < 2; ++qblk) {
    floatx4 lr;
    for (int r = 0; r < 4; ++r) lr[r] = 1.0f / la[qblk][r];
    int qg = qt * 128 + wid * 32 + qblk * 16 + quad * 4;
    for (int df = 0; df < 4; ++df) {
      int col = h * HDIM + df * 16 + m16;
      size_t base = (size_t)(b * SEQ + qg) * CH + col;
      ao[base + 0 * CH] = f2bf(o[qblk][df][0] * lr[0]);
      ao[base + 1 * CH] = f2bf(o[qblk][df][1] * lr[1]);
      ao[base + 2 * CH] = f2bf(o[qblk][df][2] * lr[2]);
      ao[base + 3 * CH] = f2bf(o[qblk][df][3] * lr[3]);
    }
  }
}

// ---------------------------------------------------------------------------
extern "C" void kernel_launch(void* const* d_in, const int* in_sizes, int n_in,
                              void* d_out, int out_size, void* d_ws, size_t ws_size,
                              hipStream_t stream) {
  const float* x    = (const float*)d_in[0];
  const float* gsc  = (const float*)d_in[1];
  const float* gbs  = (const float*)d_in[2];
  const float* wqkv = (const float*)d_in[3];
  const float* bqkv = (const float*)d_in[4];
  const float* wout = (const float*)d_in[5];
  const float* bout = (const float*)d_in[6];
  float* out = (float*)d_out;

  char* ws = (char*)d_ws;
  unsigned short* xn    = (unsigned short*)(ws);                 // 8 MB (8192x512)
  unsigned short* wqkvt = (unsigned short*)(ws + 8388608);       // 1.5 MB (1536x512)
  unsigned short* woutt = (unsigned short*)(ws + 9961472);       // 0.5 MB (512x512)
  unsigned short* qb    = (unsigned short*)(ws + 10485760);      // 8 MB (64,1024,64)
  unsigned short* kb    = (unsigned short*)(ws + 18874368);      // 8 MB (64,1024,64)
  unsigned short* vtb   = (unsigned short*)(ws + 27262976);      // 8 MB (64,64,1024)
  unsigned short* ao    = (unsigned short*)(ws + 35651584);      // 8 MB (8192x512)

  prep_kernel<<<512, 1024, 0, stream>>>(wqkv, wout, x, gsc, gbs, wqkvt, woutt, xn);
  gemm_bt_kernel<0, 128><<<dim3(64, 12), 256, 0, stream>>>(
      xn, wqkvt, 512, 1536, bqkv, nullptr, nullptr, qb, kb, vtb);
  attn_kernel<<<dim3(64, 8), 256, 0, stream>>>(qb, kb, vtb, ao);
  gemm_bt_kernel<1, 64><<<dim3(128, 4), 256, 0, stream>>>(
      ao, woutt, 512, 512, bout, x, out, nullptr, nullptr, nullptr);
}

// Round 4
// 142.380 us; speedup vs baseline: 1.0214x; 1.0214x over previous
//
#include <hip/hip_runtime.h>
#include <hip/hip_bf16.h>

// B=8, H=W=32 (seq=1024), C=512, heads=8, head_dim=64, groups=32
#define SEQ   1024
#define CH    512
#define NHEAD 8
#define HDIM  64
#define BATCH 8

using short8  = __attribute__((ext_vector_type(8))) short;
using short4v = __attribute__((ext_vector_type(4))) short;
using floatx4 = __attribute__((ext_vector_type(4))) float;
using uint4v  = __attribute__((ext_vector_type(4))) unsigned int;

#if __has_builtin(__builtin_amdgcn_exp2f)
#define EXP2F __builtin_amdgcn_exp2f
#else
#define EXP2F exp2f
#endif

__device__ inline unsigned short f2bf(float f) {
  __hip_bfloat16 h = __float2bfloat16(f);
  return __builtin_bit_cast(unsigned short, h);
}

// packed f32x2 -> bf16x2 (RNE), single VALU inst; low half = first arg
__device__ inline unsigned int cvt_pk_bf16(float lo, float hi) {
  unsigned int r;
  asm("v_cvt_pk_bf16_f32 %0, %1, %2" : "=v"(r) : "v"(lo), "v"(hi));
  return r;
}

// async 16B global->LDS DMA (lane-linear LDS dest required)
__device__ inline void load_lds16(const void* g, void* l) {
  __builtin_amdgcn_global_load_lds(
      (const __attribute__((address_space(1))) unsigned int*)g,
      (__attribute__((address_space(3))) unsigned int*)l, 16, 0, 0);
}

// ---------------------------------------------------------------------------
// K1 (fused): blocks 0..255 = GroupNorm for one (b,g): the whole 1024x16
// slice (64 KB) is staged in LDS, stats computed in one pass, normalized
// bf16 written back -- x is read ONCE.
// Blocks 256..447: wqkv transpose (64x64 tiles); 448..511: wout transpose.
// ---------------------------------------------------------------------------
__global__ __launch_bounds__(1024) void prep_kernel(
    const float* __restrict__ wqkv, const float* __restrict__ wout,
    const float* __restrict__ x, const float* __restrict__ gsc,
    const float* __restrict__ gbs,
    unsigned short* __restrict__ wqkvt, unsigned short* __restrict__ woutt,
    unsigned short* __restrict__ xn) {
  __shared__ float SH[16416];   // 64 KB tile + 32 floats reduce scratch
  const int blk = blockIdx.x, tid = threadIdx.x;

  if (blk >= 256) {
    // ---- weight transpose, 64x64 tile, bf16 out ----
    const float* src; unsigned short* dst; int C, bx, by;
    if (blk < 448) { int t = blk - 256; src = wqkv; dst = wqkvt; C = 1536; bx = t % 24; by = t / 24; }
    else           { int t = blk - 448; src = wout; dst = woutt; C = 512;  bx = t & 7;  by = t >> 3; }
    float (*T)[65] = (float(*)[65])SH;
    int tx = tid & 63, ty = tid >> 6;            // ty 0..15
    for (int j = 0; j < 4; ++j)
      T[ty + j * 16][tx] = src[(size_t)(by * 64 + ty + j * 16) * C + bx * 64 + tx];
    __syncthreads();
    for (int j = 0; j < 4; ++j)
      dst[(size_t)(bx * 64 + ty + j * 16) * 512 + by * 64 + tx] = f2bf(T[tx][ty + j * 16]);
    return;
  }

  // ---- GroupNorm, one (b,g) per block ----
  const int b = blk >> 5, g = blk & 31;
  const size_t base = (size_t)b * SEQ * CH + g * 16;

  float s = 0.f, sq = 0.f;
  for (int i = 0; i < 4; ++i) {
    int c = (i << 10) + tid;                     // 4096 float4 chunks
    int r = c >> 2, c4 = (c & 3) << 2;
    float4 v = *(const float4*)(x + base + (size_t)r * CH + c4);
    *(float4*)&SH[c << 2] = v;
    s  += v.x + v.y + v.z + v.w;
    sq += v.x * v.x + v.y * v.y + v.z * v.z + v.w * v.w;
  }
  for (int off = 1; off < 64; off <<= 1) {
    s  += __shfl_xor(s, off);
    sq += __shfl_xor(sq, off);
  }
  const int wid = tid >> 6, lane = tid & 63;
  if (lane == 0) { SH[16384 + wid] = s; SH[16400 + wid] = sq; }
  __syncthreads();
  float ts = 0.f, tq = 0.f;
  for (int i = 0; i < 16; ++i) { ts += SH[16384 + i]; tq += SH[16400 + i]; }
  const float inv_n = 1.0f / 16384.0f;
  float mean = ts * inv_n;
  float var  = tq * inv_n - mean * mean;
  float rstd = rsqrtf(var + 1e-6f);

  int c4 = (tid & 3) << 2;
  float4 sc = *(const float4*)(gsc + g * 16 + c4);
  float4 bs = *(const float4*)(gbs + g * 16 + c4);
  for (int i = 0; i < 4; ++i) {
    int c = (i << 10) + tid;
    int r = c >> 2;
    float4 v = *(const float4*)&SH[c << 2];
    ushort4 o;
    o.x = f2bf((v.x - mean) * rstd * sc.x + bs.x);
    o.y = f2bf((v.y - mean) * rstd * sc.y + bs.y);
    o.z = f2bf((v.z - mean) * rstd * sc.z + bs.z);
    o.w = f2bf((v.w - mean) * rstd * sc.w + bs.w);
    *(ushort4*)(xn + base + (size_t)r * CH + c4) = o;
  }
}

// ---------------------------------------------------------------------------
// K2/K4: GEMM C = A(MxK) * Bt(NxK)^T, bf16 in, fp32 acc, MTILE x 128 tile.
// Grid is (m-tile, n-tile) so blocks sharing an A-tile get the same
// linear%8 -> same XCD (L2 locality).  BK=64, global_load_lds staging,
// XOR-swizzled LDS.  Epilogues via LDS -> 16B global stores.
// EPI 0 (MTILE=128, QKV): +bias; q scaled (1/64)*log2e; q/k -> (h,s,d);
//     v -> transposed vt (h,d,s) with s permuted within 32-blocks so attn
//     PV P-frags form 16x16x32 A-operands with zero cross-lane ops.
// EPI 1 (MTILE=64, out):  +bias +residual, fp32 out.
// ---------------------------------------------------------------------------
template <int EPI, int MTILE>
__global__ __launch_bounds__(256) void gemm_bt_kernel(
    const unsigned short* __restrict__ A, const unsigned short* __restrict__ Bt,
    int K, int N,
    const float* __restrict__ bias, const float* __restrict__ resid,
    float* __restrict__ outf,
    unsigned short* __restrict__ qb, unsigned short* __restrict__ kb,
    unsigned short* __restrict__ vtb) {
  constexpr int SMSZ = (MTILE == 128) ? 17408 : 16896;
  constexpr int NI   = (MTILE == 128) ? 4 : 2;
  __shared__ alignas(16) unsigned short SM[SMSZ];
  unsigned short* LA = SM;                 // MTILE x 64, swizzled
  unsigned short* LB = SM + MTILE * 64;    // 128 x 64, swizzled

  const int tid = threadIdx.x;
  const int wid = tid >> 6, lane = tid & 63;
  const int quad = lane >> 4, m16 = lane & 15;
  const int sw = m16 & 7;
  const int wm = (MTILE == 128) ? (wid & 1) * 64 : 0;
  const int wn = (MTILE == 128) ? (wid >> 1) * 64 : wid * 32;
  const int m0 = blockIdx.x * MTILE, n0 = blockIdx.y * 128;

  floatx4 acc[4][NI];
  for (int i = 0; i < 4; ++i)
    for (int j = 0; j < NI; ++j) acc[i][j] = 0.f;

  for (int k0 = 0; k0 < K; k0 += 64) {
    for (int i = 0; i < MTILE / 32; ++i) {
      int c = i * 256 + tid;
      int r = c >> 3, kc = c & 7;
      load_lds16(A + (size_t)(m0 + r) * K + k0 + ((kc ^ (r & 7)) << 3), &LA[c << 3]);
    }
    for (int i = 0; i < 4; ++i) {
      int c = i * 256 + tid;
      int r = c >> 3, kc = c & 7;
      load_lds16(Bt + (size_t)(n0 + r) * K + k0 + ((kc ^ (r & 7)) << 3), &LB[c << 3]);
    }
    __syncthreads();
    for (int kq = 0; kq < 2; ++kq) {
      int csw = (((kq << 2) + quad) ^ sw) << 3;
      short8 af[4], bf[NI];
      for (int mi = 0; mi < 4; ++mi)
        af[mi] = *(const short8*)&LA[(wm + mi * 16 + m16) * 64 + csw];
      for (int ni = 0; ni < NI; ++ni)
        bf[ni] = *(const short8*)&LB[(wn + ni * 16 + m16) * 64 + csw];
      for (int mi = 0; mi < 4; ++mi)
        for (int ni = 0; ni < NI; ++ni)
          acc[mi][ni] = __builtin_amdgcn_mfma_f32_16x16x32_bf16(af[mi], bf[ni], acc[mi][ni], 0, 0, 0);
    }
    __syncthreads();
  }

  // C/D layout: row = quad*4+reg, col = lane&15
  const int b = m0 >> 10;
  if (EPI == 0) {
    const int part = n0 >> 9;                // 0=q 1=k 2=v (block-uniform)
    if (part < 2) {
      const float qscale = (part == 0) ? 0.0225421381f : 1.0f;  // (1/64)*log2e
      unsigned short* dst = (part == 0) ? qb : kb;
      for (int mi = 0; mi < 4; ++mi)
        for (int ni = 0; ni < 4; ++ni) {
          int ln = wn + ni * 16 + m16;
          float bb = bias[n0 + ln];
          for (int reg = 0; reg < 4; ++reg)
            SM[(wm + mi * 16 + quad * 4 + reg) * 136 + ln] =
                f2bf((acc[mi][ni][reg] + bb) * qscale);
        }
      __syncthreads();
      const int colb = n0 & 511;
      for (int j = 0; j < 8; ++j) {
        int c = j * 256 + tid;               // 2048 16B chunks
        int m = c >> 4, n8 = (c & 15) * 8;
        int h = (colb + n8) >> 6, d = n8 & 63;
        int sp = (m0 & 1023) + m;
        int4 v = *(const int4*)&SM[m * 136 + n8];
        *(int4*)(dst + (((size_t)(b * NHEAD + h)) * SEQ + sp) * HDIM + d) = v;
      }
    } else {
      // v: transpose [n][m], m permuted within 32-blocks (slot = 32*(mblk>>1)
      // + 8*quad + 4*(mblk&1) + reg) for attn's K=32 PV A-operands
      for (int mi = 0; mi < 4; ++mi)
        for (int ni = 0; ni < 4; ++ni) {
          int ln = wn + ni * 16 + m16;
          float bb = bias[n0 + ln];
          int mblk = (wm >> 4) + mi;
          int sbase = 32 * (mblk >> 1) + 8 * quad + 4 * (mblk & 1);
          for (int reg = 0; reg < 4; ++reg)
            SM[ln * 136 + sbase + reg] = f2bf(acc[mi][ni][reg] + bb);
        }
      __syncthreads();
      int hbase = (n0 - 1024) >> 6;
      for (int j = 0; j < 8; ++j) {
        int c = j * 256 + tid;
        int ld = c >> 4, sp8 = (c & 15) * 8;
        int h = hbase + (ld >> 6), d = ld & 63;
        int4 v = *(const int4*)&SM[ld * 136 + sp8];
        *(int4*)(vtb + ((size_t)(b * NHEAD + h) * HDIM + d) * SEQ + (m0 & 1023) + sp8) = v;
      }
    }
  } else {
    float* SMf = (float*)SM;                 // 64 x 132 fp32
    for (int mi = 0; mi < 4; ++mi)
      for (int ni = 0; ni < NI; ++ni) {
        int ln = wn + ni * 16 + m16;
        float bb = bias[n0 + ln];
        for (int reg = 0; reg < 4; ++reg)
          SMf[(mi * 16 + quad * 4 + reg) * 132 + ln] = acc[mi][ni][reg] + bb;
      }
    __syncthreads();
    for (int j = 0; j < 8; ++j) {
      int c = j * 256 + tid;                 // 2048 float4 chunks
      int m = c >> 5, n4 = (c & 31) * 4;
      size_t idx = (size_t)(m0 + m) * N + n0 + n4;
      float4 v = *(const float4*)&SMf[m * 132 + n4];
      float4 rr = *(const float4*)&resid[idx];
      v.x += rr.x; v.y += rr.y; v.z += rr.z; v.w += rr.w;
      *(float4*)&outf[idx] = v;
    }
  }
}

// ---------------------------------------------------------------------------
// K3: flash attention.  r3 post-mortem: halving LDS traffic was neutral
// because dbuf LDS (64KB) capped occupancy at 8 waves/CU -- attn is
// LATENCY-bound, not LDS-BW-bound.  This round: single 32KB buffer ->
// 4 blocks/CU (16 waves/CU); cross-block TLP hides staging latency (m114).
// kt-body restructured per-u (produce P-frag u, immediately consume in PV)
// to keep VGPR <= 128 for the 4-block occupancy.  Epilogue now routes o
// through the freed LDS (normalized f32) and writes coalesced 16B chunks
// (was 16 scalar 2B strided stores/lane).
// Keeps: 32 q-rows/wave, raw v_exp_f32, packed cvt_pk_bf16, ones-column
// MFMA denominator, setprio on MFMA clusters.
// ---------------------------------------------------------------------------
__global__ __launch_bounds__(256, 4) void attn_kernel(
    const unsigned short* __restrict__ qb, const unsigned short* __restrict__ kb,
    const unsigned short* __restrict__ vtb, unsigned short* __restrict__ ao) {
  const int head = blockIdx.x, qt = blockIdx.y;
  const int b = head >> 3, h = head & 7;
  const int tid = threadIdx.x;
  const int wid = tid >> 6, lane = tid & 63;
  const int quad = lane >> 4, m16 = lane & 15;
  const int sw = m16 & 7;

  __shared__ alignas(16) unsigned short SMEM[16384];   // 32 KB
  unsigned short* sK = SMEM;           // 128x64, swizzled (16 KB)
  unsigned short* sV = SMEM + 8192;    // Vt 64x128 (s permuted), swizzled (16 KB)

  const unsigned short* kbase = kb  + (size_t)head * SEQ * HDIM;
  const unsigned short* vbase = vtb + (size_t)head * HDIM * SEQ;

  // Q fragments for two 16-row q-blocks (pre-scaled by (1/64)*log2e upstream)
  short8 aq[2][2];
  for (int qblk = 0; qblk < 2; ++qblk) {
    const size_t qrow = (size_t)head * SEQ + qt * 128 + wid * 32 + qblk * 16 + m16;
    aq[qblk][0] = *(const short8*)(qb + qrow * HDIM + quad * 8);
    aq[qblk][1] = *(const short8*)(qb + qrow * HDIM + 32 + quad * 8);
  }

  const unsigned int onep = 0x3F803F80u;               // bf16(1.0) x2
  const short8 vones = __builtin_bit_cast(short8, (uint4v){onep, onep, onep, onep});

  floatx4 la[2];                                       // denominators, D-layout
  floatx4 o[2][4];
  for (int qblk = 0; qblk < 2; ++qblk) {
    la[qblk] = 0.f;
    for (int df = 0; df < 4; ++df) o[qblk][df] = 0.f;
  }

  for (int kt = 0; kt < 8; ++kt) {
    if (kt) __syncthreads();           // prior compute done before overwrite
    // stage K tile (128x64) and Vt tile (64x128), 4+4 chunks per thread
    for (int i = 0; i < 4; ++i) {
      int c = i * 256 + tid;
      int r = c >> 3, kc = c & 7;
      load_lds16(kbase + (kt * 128 + r) * HDIM + ((kc ^ (r & 7)) << 3), &sK[c << 3]);
    }
    for (int i = 0; i < 4; ++i) {
      int c = i * 256 + tid;
      int d = c >> 4, kc = c & 15;
      load_lds16(vbase + d * SEQ + kt * 128 + ((kc ^ (d & 7)) << 3), &sV[c << 3]);
    }
    __syncthreads();                   // vmcnt(0) drained -> tiles ready

    // per-u: QK^T for the 2 sub-frags -> exp2 -> pack -> PV immediately.
    // sf=2u+t -> A-operand k=quad*8+4t+r.  pw live range = one u (8 VGPR).
    for (int u = 0; u < 4; ++u) {
      unsigned int pw[2][4];
      for (int t = 0; t < 2; ++t) {
        const int sf = u * 2 + t;
        const int rb = (sf * 16 + m16) * 64;
        short8 k0 = *(const short8*)&sK[rb + ((quad ^ sw) << 3)];
        short8 k1 = *(const short8*)&sK[rb + (((4 + quad) ^ sw) << 3)];
        floatx4 s0 = 0.f, s1 = 0.f;
        __builtin_amdgcn_s_setprio(1);
        s0 = __builtin_amdgcn_mfma_f32_16x16x32_bf16(k0, aq[0][0], s0, 0, 0, 0);
        s0 = __builtin_amdgcn_mfma_f32_16x16x32_bf16(k1, aq[0][1], s0, 0, 0, 0);
        s1 = __builtin_amdgcn_mfma_f32_16x16x32_bf16(k0, aq[1][0], s1, 0, 0, 0);
        s1 = __builtin_amdgcn_mfma_f32_16x16x32_bf16(k1, aq[1][1], s1, 0, 0, 0);
        __builtin_amdgcn_s_setprio(0);
        pw[0][t * 2 + 0] = cvt_pk_bf16(EXP2F(s0[0]), EXP2F(s0[1]));
        pw[0][t * 2 + 1] = cvt_pk_bf16(EXP2F(s0[2]), EXP2F(s0[3]));
        pw[1][t * 2 + 0] = cvt_pk_bf16(EXP2F(s1[0]), EXP2F(s1[1]));
        pw[1][t * 2 + 1] = cvt_pk_bf16(EXP2F(s1[2]), EXP2F(s1[3]));
      }
      const short8 pf0 = __builtin_bit_cast(
          short8, (uint4v){pw[0][0], pw[0][1], pw[0][2], pw[0][3]});
      const short8 pf1 = __builtin_bit_cast(
          short8, (uint4v){pw[1][0], pw[1][1], pw[1][2], pw[1][3]});
      const int chunk = ((u * 4 + quad) ^ sw) << 3;
      __builtin_amdgcn_s_setprio(1);
      for (int df = 0; df < 4; ++df) {
        short8 bv = *(const short8*)&sV[(df * 16 + m16) * 128 + chunk];
        o[0][df] = __builtin_amdgcn_mfma_f32_16x16x32_bf16(pf0, bv, o[0][df], 0, 0, 0);
        o[1][df] = __builtin_amdgcn_mfma_f32_16x16x32_bf16(pf1, bv, o[1][df], 0, 0, 0);
      }
      la[0] = __builtin_amdgcn_mfma_f32_16x16x32_bf16(pf0, vones, la[0], 0, 0, 0);
      la[1] = __builtin_amdgcn_mfma_f32_16x16x32_bf16(pf1, vones, la[1], 0, 0, 0);
      __builtin_amdgcn_s_setprio(0);
    }
  }
  __syncthreads();                     // all compute done; reuse LDS as scratch

  // normalize into f32 scratch [128][64] (exactly 32KB), then coalesced write
  float* Sc = (float*)SMEM;
  for (int qblk = 0; qblk < 2; ++qblk) {
    floatx4 lr;
    for (int r = 0; r < 4; ++r) lr[r] = 1.0f / la[qblk][r];
    const int row0 = wid * 32 + qblk * 16 + quad * 4;
    for (int df = 0; df < 4; ++df) {
      const int col = df * 16 + m16;
      Sc[(row0 + 0) * 64 + col] = o[qblk][df][0] * lr[0];
      Sc[(row0 + 1) * 64 + col] = o[qblk][df][1] * lr[1];
      Sc[(row0 + 2) * 64 + col] = o[qblk][df][2] * lr[2];
      Sc[(row0 + 3) * 64 + col] = o[qblk][df][3] * lr[3];
    }
  }
  __syncthreads();
  for (int j = 0; j < 4; ++j) {
    int c = j * 256 + tid;             // 1024 8-col chunks
    int m = c >> 3, n8 = (c & 7) * 8;
    floatx4 v0 = *(const floatx4*)&Sc[m * 64 + n8];
    floatx4 v1 = *(const floatx4*)&Sc[m * 64 + n8 + 4];
    int4 w;
    w.x = (int)cvt_pk_bf16(v0[0], v0[1]);
    w.y = (int)cvt_pk_bf16(v0[2], v0[3]);
    w.z = (int)cvt_pk_bf16(v1[0], v1[1]);
    w.w = (int)cvt_pk_bf16(v1[2], v1[3]);
    *(int4*)(ao + (size_t)(b * SEQ + qt * 128 + m) * CH + h * HDIM + n8) = w;
  }
}

// ---------------------------------------------------------------------------
extern "C" void kernel_launch(void* const* d_in, const int* in_sizes, int n_in,
                              void* d_out, int out_size, void* d_ws, size_t ws_size,
                              hipStream_t stream) {
  const float* x    = (const float*)d_in[0];
  const float* gsc  = (const float*)d_in[1];
  const float* gbs  = (const float*)d_in[2];
  const float* wqkv = (const float*)d_in[3];
  const float* bqkv = (const float*)d_in[4];
  const float* wout = (const float*)d_in[5];
  const float* bout = (const float*)d_in[6];
  float* out = (float*)d_out;

  char* ws = (char*)d_ws;
  unsigned short* xn    = (unsigned short*)(ws);                 // 8 MB (8192x512)
  unsigned short* wqkvt = (unsigned short*)(ws + 8388608);       // 1.5 MB (1536x512)
  unsigned short* woutt = (unsigned short*)(ws + 9961472);       // 0.5 MB (512x512)
  unsigned short* qb    = (unsigned short*)(ws + 10485760);      // 8 MB (64,1024,64)
  unsigned short* kb    = (unsigned short*)(ws + 18874368);      // 8 MB (64,1024,64)
  unsigned short* vtb   = (unsigned short*)(ws + 27262976);      // 8 MB (64,64,1024)
  unsigned short* ao    = (unsigned short*)(ws + 35651584);      // 8 MB (8192x512)

  prep_kernel<<<512, 1024, 0, stream>>>(wqkv, wout, x, gsc, gbs, wqkvt, woutt, xn);
  gemm_bt_kernel<0, 128><<<dim3(64, 12), 256, 0, stream>>>(
      xn, wqkvt, 512, 1536, bqkv, nullptr, nullptr, qb, kb, vtb);
  attn_kernel<<<dim3(64, 8), 256, 0, stream>>>(qb, kb, vtb, ao);
  gemm_bt_kernel<1, 64><<<dim3(128, 4), 256, 0, stream>>>(
      ao, woutt, 512, 512, bout, x, out, nullptr, nullptr, nullptr);
}